// Round 1
// baseline (79.794 us; speedup 1.0000x reference)
//
#include <hip/hip_runtime.h>

// ChamferLoss: B=4, C=3, N=M=8192 fp32.
// loss = 2 * mean_b( sum_n min_m ||q_n - r_m||^2 ), clamp >= 0.
// s(n,m) = q.r - 0.5*r^2 via v_mfma_f32_32x32x16_bf16, fp32 split as bf16
// hi+lo across K. Fragment math identical to R10 (verified absmax 0.0).
//
// ROUND 11 (structural): two-kernel pipeline -> prep + single fused kernel.
//  K0 chamfer_prep: convert each ref ONCE into the A-fragment image in ws
//    (1 MiB). Old K1 converted each ref 16x (70 VALU instr/thread prologue
//    + ds_writes + barrier before any MFMA). Also zeroes out[0].
//  K1 chamfer_main: grid (128,4) = 512 blocks = 2/CU = one dispatch round.
//    Each block owns 64 queries (2 chunks), scans ALL 8192 refs in 8 phases
//    of 1024, staging fragments via async global_load_lds (16B, double-
//    buffered, counted vmcnt(4) -- never drained to 0 in the loop -- with
//    raw s_barrier; T3/T4 pattern). Per-wave running max -> cross-wave LDS
//    max -> d = max(q^2 - 2*smax, 0) -> block sum -> one atomicAdd.
//  Eliminates: partial[] 2 MiB round-trip, K2 dispatch, 16x re-conversion.

#define NPTS 8192
#define NB   4
#define RR   8        // ref ranges (1024 refs each) = staging phases
#define WPB  8        // waves per block
#define BT   (WPB * 64)

typedef float f32x16 __attribute__((ext_vector_type(16)));
typedef short bf16x8 __attribute__((ext_vector_type(8)));

static __device__ __forceinline__ unsigned int f2bf(float f) {
    unsigned int u = __float_as_uint(f);
    u += 0x7FFF + ((u >> 16) & 1);          // RNE
    return u >> 16;
}
static __device__ __forceinline__ float bf2f(unsigned int s) {
    return __uint_as_float(s << 16);
}

// ---- K0: one-time ref -> A-fragment conversion (exact old LDS image) ----
__global__ __launch_bounds__(512) void chamfer_prep(
    const float* __restrict__ pc1w,      // refs [B,3,N]
    uint4* __restrict__ wsA,             // [B][RR][32 chunks][64] uint4 = 1 MiB
    float* __restrict__ out)
{
    const int g = blockIdx.x * 512 + threadIdx.x;   // 0..32767, one ref each
    if (g == 0) out[0] = 0.0f;                      // K1 accumulates after
    const int b = g >> 13, i = g & (NPTS - 1);
    const float* refb = pc1w + b * 3 * NPTS;
    float x = refb[i], y = refb[NPTS + i], z = refb[2 * NPTS + i];
    unsigned xh = f2bf(x), yh = f2bf(y), zh = f2bf(z);
    unsigned xl = f2bf(x - bf2f(xh));
    unsigned yl = f2bf(y - bf2f(yh));
    unsigned zl = f2bf(z - bf2f(zh));
    float h = -0.5f * (x * x + y * y + z * z);
    unsigned hh = f2bf(h);
    unsigned hl = f2bf(h - bf2f(hh));
    const int rr = i >> 10, ir = i & 1023, c = ir >> 5, l = ir & 31;
    // A k0..7 = [xh,xl,xh,yh,yl,yh,zh,zl], k8..15 = [zh,hh,hl,0,...]
    uint4* dst = wsA + (((b * RR + rr) * 32 + c) << 6);
    dst[l]      = make_uint4(xh | (xl << 16), xh | (yh << 16),
                             yl | (yh << 16), zh | (zl << 16));
    dst[32 + l] = make_uint4(zh | (hh << 16), hl, 0u, 0u);
}

// async copy of one wave's share of a 1024-ref range (2048 uint4) into LDS
static __device__ __forceinline__ void stage_range(
    const uint4* __restrict__ gsrc, uint4* lbase, int wave, int lane)
{
#pragma unroll
    for (int j = 0; j < 4; ++j) {
        const int idx = j * 512 + wave * 64;        // wave-uniform part
        const uint4* gp = gsrc + idx + lane;        // per-lane global src
        uint4* lp = lbase + idx;                    // HW adds lane*16 to dest
        __builtin_amdgcn_global_load_lds(
            (const __attribute__((address_space(1))) unsigned int*)gp,
            (__attribute__((address_space(3))) unsigned int*)lp, 16, 0, 0);
    }
}

static __device__ __forceinline__ bf16x8 make_bfrag(float x, float y, float z,
                                                    int lane)
{
    unsigned xh = f2bf(x), yh = f2bf(y), zh = f2bf(z);
    unsigned xl = f2bf(x - bf2f(xh));
    unsigned yl = f2bf(y - bf2f(yh));
    unsigned zl = f2bf(z - bf2f(zh));
    // B k0..7 = [xh,xh,xl,yh,yh,yl,zh,zh], k8..15 = [zl,1,1,0,...]
    uint4 bu = (lane < 32)
        ? make_uint4(xh | (xh << 16), xl | (yh << 16),
                     yh | (yl << 16), zh | (zh << 16))
        : make_uint4(zl | (0x3F80u << 16), 0x3F80u, 0u, 0u);
    return __builtin_bit_cast(bf16x8, bu);
}

static __device__ __forceinline__ void proc_chunk(
    uint4 av, bf16x8 bq0, bf16x8 bq1, const f32x16& zero,
    float& rma0, float& rma1, float& rma2, float& rma3,
    float& rmb0, float& rmb1, float& rmb2, float& rmb3)
{
    bf16x8 aa = __builtin_bit_cast(bf16x8, av);
    f32x16 d0 = __builtin_amdgcn_mfma_f32_32x32x16_bf16(aa, bq0, zero, 0, 0, 0);
    f32x16 d1 = __builtin_amdgcn_mfma_f32_32x32x16_bf16(aa, bq1, zero, 0, 0, 0);
    rma0 = fmaxf(rma0, fmaxf(d0[0],  d0[1]));   // rows = refs
    rma0 = fmaxf(rma0, fmaxf(d0[2],  d0[3]));
    rma1 = fmaxf(rma1, fmaxf(d0[4],  d0[5]));
    rma1 = fmaxf(rma1, fmaxf(d0[6],  d0[7]));
    rma2 = fmaxf(rma2, fmaxf(d0[8],  d0[9]));
    rma2 = fmaxf(rma2, fmaxf(d0[10], d0[11]));
    rma3 = fmaxf(rma3, fmaxf(d0[12], d0[13]));
    rma3 = fmaxf(rma3, fmaxf(d0[14], d0[15]));
    rmb0 = fmaxf(rmb0, fmaxf(d1[0],  d1[1]));
    rmb0 = fmaxf(rmb0, fmaxf(d1[2],  d1[3]));
    rmb1 = fmaxf(rmb1, fmaxf(d1[4],  d1[5]));
    rmb1 = fmaxf(rmb1, fmaxf(d1[6],  d1[7]));
    rmb2 = fmaxf(rmb2, fmaxf(d1[8],  d1[9]));
    rmb2 = fmaxf(rmb2, fmaxf(d1[10], d1[11]));
    rmb3 = fmaxf(rmb3, fmaxf(d1[12], d1[13]));
    rmb3 = fmaxf(rmb3, fmaxf(d1[14], d1[15]));
}

// ---- K1: fused main kernel ----
__global__ __launch_bounds__(BT, 4) void chamfer_main(
    const float* __restrict__ pc2,       // queries [B,3,N]
    const uint4* __restrict__ wsA,       // precomputed A-fragments
    float* __restrict__ out)
{
    __shared__ uint4 abuf[2][2048];      // 64 KB double buffer (1024 refs each)
    __shared__ float red[WPB][64];       // cross-wave max partials
    const int tid  = threadIdx.x;
    const int wave = tid >> 6;
    const int lane = tid & 63;
    const int b    = blockIdx.y;
    const int qc0  = blockIdx.x * 2;     // 2 query chunks = 64 queries / block

    // query loads FIRST (so their vmcnt drain doesn't drain the stage below)
    const float* qb = pc2 + b * 3 * NPTS;
    const int qn0 = qc0 * 32 + (lane & 31);
    const int qn1 = qn0 + 32;
    float x0 = qb[qn0], y0 = qb[NPTS + qn0], z0 = qb[2 * NPTS + qn0];
    float x1 = qb[qn1], y1 = qb[NPTS + qn1], z1 = qb[2 * NPTS + qn1];

    // issue phase-0 staging, then convert queries under the load latency
    const uint4* wsb = wsA + (size_t)b * RR * 2048;
    stage_range(wsb, abuf[0], wave, lane);

    bf16x8 bq0 = make_bfrag(x0, y0, z0, lane);
    bf16x8 bq1 = make_bfrag(x1, y1, z1, lane);

    f32x16 zero;
#pragma unroll
    for (int i = 0; i < 16; ++i) zero[i] = 0.0f;

    float rma0 = -3e38f, rma1 = -3e38f, rma2 = -3e38f, rma3 = -3e38f;
    float rmb0 = -3e38f, rmb1 = -3e38f, rmb2 = -3e38f, rmb3 = -3e38f;

#pragma unroll
    for (int p = 0; p < RR; ++p) {
        if (p != RR - 1) {
            stage_range(wsb + (p + 1) * 2048, abuf[(p + 1) & 1], wave, lane);
            // 8 outstanding -> wait until only next-phase's 4 remain
            asm volatile("s_waitcnt vmcnt(4)" ::: "memory");
        } else {
            asm volatile("s_waitcnt vmcnt(0)" ::: "memory");
        }
        __builtin_amdgcn_s_barrier();            // buf[p&1] fully staged
        asm volatile("" ::: "memory");

        // this wave's 4 chunks (128 refs) x 2 query chunks = 8 MFMAs
        const uint4* src = &abuf[p & 1][wave * 256];
        uint4 av0 = src[lane];
        uint4 av1 = src[64 + lane];
        uint4 av2 = src[128 + lane];
        uint4 av3 = src[192 + lane];
        proc_chunk(av0, bq0, bq1, zero, rma0, rma1, rma2, rma3,
                   rmb0, rmb1, rmb2, rmb3);
        proc_chunk(av1, bq0, bq1, zero, rma0, rma1, rma2, rma3,
                   rmb0, rmb1, rmb2, rmb3);
        proc_chunk(av2, bq0, bq1, zero, rma0, rma1, rma2, rma3,
                   rmb0, rmb1, rmb2, rmb3);
        proc_chunk(av3, bq0, bq1, zero, rma0, rma1, rma2, rma3,
                   rmb0, rmb1, rmb2, rmb3);

        if (p != RR - 1) {
            asm volatile("" ::: "memory");       // reads done before next
            __builtin_amdgcn_s_barrier();        // overwrite of buf[(p+1)&1]
        }
    }

    float rma = fmaxf(fmaxf(rma0, rma1), fmaxf(rma2, rma3));
    float rmb = fmaxf(fmaxf(rmb0, rmb1), fmaxf(rmb2, rmb3));
    // lanes l and l^32 hold the two row-halves of the same query column
    rma = fmaxf(rma, __shfl_xor(rma, 32, 64));
    rmb = fmaxf(rmb, __shfl_xor(rmb, 32, 64));
    if (lane < 32) {
        red[wave][lane]      = rma;
        red[wave][32 + lane] = rmb;
    }
    __syncthreads();

    if (tid < 64) {                              // wave 0 finalizes 64 queries
        float smax = red[0][tid];
#pragma unroll
        for (int w = 1; w < WPB; ++w) smax = fmaxf(smax, red[w][tid]);
        const int n = qc0 * 32 + tid;
        float qx = qb[n], qy = qb[NPTS + n], qz = qb[2 * NPTS + n];
        float d = fmaxf(qx * qx + qy * qy + qz * qz - 2.0f * smax, 0.0f);
#pragma unroll
        for (int off = 32; off > 0; off >>= 1)
            d += __shfl_down(d, off, 64);
        if (tid == 0)
            atomicAdd(out, d * (2.0f / NB));     // 2 * mean over batches
    }
}

extern "C" void kernel_launch(void* const* d_in, const int* in_sizes, int n_in,
                              void* d_out, int out_size, void* d_ws, size_t ws_size,
                              hipStream_t stream) {
    const float* pc2  = (const float*)d_in[0];
    const float* pc1w = (const float*)d_in[1];
    float* out = (float*)d_out;
    uint4* wsA = (uint4*)d_ws;                   // B*RR*2048*16 B = 1 MiB

    chamfer_prep<<<NB * NPTS / 512, 512, 0, stream>>>(pc1w, wsA, out);
    dim3 g(128, NB);                             // 512 blocks = 2/CU, one round
    chamfer_main<<<g, BT, 0, stream>>>(pc2, wsA, out);
}

// Round 2
// 76.060 us; speedup vs baseline: 1.0491x; 1.0491x over previous
//
#include <hip/hip_runtime.h>

// ChamferLoss: B=4, C=3, N=M=8192 fp32.
// loss = 2 * mean_b( sum_n min_m ||q_n - r_m||^2 ), clamp >= 0.
// s(n,m) = q.r - 0.5*r^2 via v_mfma_f32_32x32x16_bf16, fp32 split as bf16
// hi+lo across K. Fragment math identical to R10/R11 (verified absmax 0.0).
//
// ROUND 12: drop LDS staging entirely. R11 profile showed the harness's
// 268MB ws poison fill = 41.5us (immovable); main kernel ~30us vs ~5us model.
// Root cause: the LDS double-buffer + 2 barriers/phase + vmcnt pipeline
// staged data that has ZERO intra-block sharing (each wave reads disjoint
// chunks) and is L2-resident (1 MiB). Guide mistake #7.
//  K0 chamfer_prep: convert each ref ONCE into flat A-fragment image
//    wsA[b][chunk 0..255][64 uint4] (1 MiB). Zeroes out[0].
//  K1 chamfer_main: grid (128,4) = 512 blocks = 2/CU. Each block: 64
//    queries; wave w scans its own 32 contiguous chunks (1024 refs)
//    global->VGPR (16B loads, 1 per 2 MFMAs, pipelined 1 ahead, unroll 4).
//    NO barriers in the loop. Cross-wave max via 2KB LDS at the end,
//    then d = max(q^2 - 2*smax, 0), block sum, one atomicAdd.

#define NPTS 8192
#define NB   4
#define WPB  8        // waves per block
#define BT   (WPB * 64)
#define CPW  32       // chunks per wave (32 refs each)

typedef float f32x16 __attribute__((ext_vector_type(16)));
typedef short bf16x8 __attribute__((ext_vector_type(8)));

static __device__ __forceinline__ unsigned int f2bf(float f) {
    unsigned int u = __float_as_uint(f);
    u += 0x7FFF + ((u >> 16) & 1);          // RNE
    return u >> 16;
}
static __device__ __forceinline__ float bf2f(unsigned int s) {
    return __uint_as_float(s << 16);
}

// ---- K0: one-time ref -> A-fragment conversion ----
__global__ __launch_bounds__(512) void chamfer_prep(
    const float* __restrict__ pc1w,      // refs [B,3,N]
    uint4* __restrict__ wsA,             // [B][256][64] uint4 = 1 MiB
    float* __restrict__ out)
{
    const int g = blockIdx.x * 512 + threadIdx.x;   // 0..32767, one ref each
    if (g == 0) out[0] = 0.0f;                      // K1 accumulates after
    const int b = g >> 13, i = g & (NPTS - 1);
    const float* refb = pc1w + b * 3 * NPTS;
    float x = refb[i], y = refb[NPTS + i], z = refb[2 * NPTS + i];
    unsigned xh = f2bf(x), yh = f2bf(y), zh = f2bf(z);
    unsigned xl = f2bf(x - bf2f(xh));
    unsigned yl = f2bf(y - bf2f(yh));
    unsigned zl = f2bf(z - bf2f(zh));
    float h = -0.5f * (x * x + y * y + z * z);
    unsigned hh = f2bf(h);
    unsigned hl = f2bf(h - bf2f(hh));
    const int c = i >> 5, l = i & 31;
    // A k0..7 = [xh,xl,xh,yh,yl,yh,zh,zl], k8..15 = [zh,hh,hl,0,...]
    uint4* dst = wsA + (((size_t)b * 256 + c) << 6);
    dst[l]      = make_uint4(xh | (xl << 16), xh | (yh << 16),
                             yl | (yh << 16), zh | (zl << 16));
    dst[32 + l] = make_uint4(zh | (hh << 16), hl, 0u, 0u);
}

static __device__ __forceinline__ bf16x8 make_bfrag(float x, float y, float z,
                                                    int lane)
{
    unsigned xh = f2bf(x), yh = f2bf(y), zh = f2bf(z);
    unsigned xl = f2bf(x - bf2f(xh));
    unsigned yl = f2bf(y - bf2f(yh));
    unsigned zl = f2bf(z - bf2f(zh));
    // B k0..7 = [xh,xh,xl,yh,yh,yl,zh,zh], k8..15 = [zl,1,1,0,...]
    uint4 bu = (lane < 32)
        ? make_uint4(xh | (xh << 16), xl | (yh << 16),
                     yh | (yl << 16), zh | (zh << 16))
        : make_uint4(zl | (0x3F80u << 16), 0x3F80u, 0u, 0u);
    return __builtin_bit_cast(bf16x8, bu);
}

static __device__ __forceinline__ void proc_chunk(
    uint4 av, bf16x8 bq0, bf16x8 bq1, const f32x16& zero,
    float& rma0, float& rma1, float& rma2, float& rma3,
    float& rmb0, float& rmb1, float& rmb2, float& rmb3)
{
    bf16x8 aa = __builtin_bit_cast(bf16x8, av);
    f32x16 d0 = __builtin_amdgcn_mfma_f32_32x32x16_bf16(aa, bq0, zero, 0, 0, 0);
    f32x16 d1 = __builtin_amdgcn_mfma_f32_32x32x16_bf16(aa, bq1, zero, 0, 0, 0);
    // each line is a 3-input max -> v_max3_f32
    rma0 = fmaxf(rma0, fmaxf(d0[0],  d0[1]));   // rows = refs
    rma0 = fmaxf(rma0, fmaxf(d0[2],  d0[3]));
    rma1 = fmaxf(rma1, fmaxf(d0[4],  d0[5]));
    rma1 = fmaxf(rma1, fmaxf(d0[6],  d0[7]));
    rma2 = fmaxf(rma2, fmaxf(d0[8],  d0[9]));
    rma2 = fmaxf(rma2, fmaxf(d0[10], d0[11]));
    rma3 = fmaxf(rma3, fmaxf(d0[12], d0[13]));
    rma3 = fmaxf(rma3, fmaxf(d0[14], d0[15]));
    rmb0 = fmaxf(rmb0, fmaxf(d1[0],  d1[1]));
    rmb0 = fmaxf(rmb0, fmaxf(d1[2],  d1[3]));
    rmb1 = fmaxf(rmb1, fmaxf(d1[4],  d1[5]));
    rmb1 = fmaxf(rmb1, fmaxf(d1[6],  d1[7]));
    rmb2 = fmaxf(rmb2, fmaxf(d1[8],  d1[9]));
    rmb2 = fmaxf(rmb2, fmaxf(d1[10], d1[11]));
    rmb3 = fmaxf(rmb3, fmaxf(d1[12], d1[13]));
    rmb3 = fmaxf(rmb3, fmaxf(d1[14], d1[15]));
}

// ---- K1: fused main kernel, no LDS staging ----
__global__ __launch_bounds__(BT, 4) void chamfer_main(
    const float* __restrict__ pc2,       // queries [B,3,N]
    const uint4* __restrict__ wsA,       // precomputed A-fragments
    float* __restrict__ out)
{
    __shared__ float red[WPB][64];       // cross-wave max partials (2 KB)
    const int tid  = threadIdx.x;
    const int wave = tid >> 6;
    const int lane = tid & 63;
    const int b    = blockIdx.y;
    const int qc0  = blockIdx.x * 2;     // 2 query chunks = 64 queries / block

    // per-lane query B-fragments (columns = lane&31 of q-chunks qc0, qc0+1)
    const float* qb = pc2 + b * 3 * NPTS;
    const int qn0 = qc0 * 32 + (lane & 31);
    const int qn1 = qn0 + 32;
    float x0 = qb[qn0], y0 = qb[NPTS + qn0], z0 = qb[2 * NPTS + qn0];
    float x1 = qb[qn1], y1 = qb[NPTS + qn1], z1 = qb[2 * NPTS + qn1];
    bf16x8 bq0 = make_bfrag(x0, y0, z0, lane);
    bf16x8 bq1 = make_bfrag(x1, y1, z1, lane);

    f32x16 zero;
#pragma unroll
    for (int i = 0; i < 16; ++i) zero[i] = 0.0f;

    float rma0 = -3e38f, rma1 = -3e38f, rma2 = -3e38f, rma3 = -3e38f;
    float rmb0 = -3e38f, rmb1 = -3e38f, rmb2 = -3e38f, rmb3 = -3e38f;

    // wave w owns 32 contiguous chunks (1024 refs); all 8 waves cover 8192
    const uint4* src = wsA + (((size_t)b * 256 + wave * CPW) << 6);

    uint4 av = src[lane];                // chunk 0 prefetched
#pragma unroll 4
    for (int c = 0; c < CPW; ++c) {
        uint4 acur = av;
        if (c + 1 < CPW)
            av = src[((c + 1) << 6) + lane];
        proc_chunk(acur, bq0, bq1, zero, rma0, rma1, rma2, rma3,
                   rmb0, rmb1, rmb2, rmb3);
    }

    float rma = fmaxf(fmaxf(rma0, rma1), fmaxf(rma2, rma3));
    float rmb = fmaxf(fmaxf(rmb0, rmb1), fmaxf(rmb2, rmb3));
    // lanes l and l^32 hold the two row-halves of the same query column
    rma = fmaxf(rma, __shfl_xor(rma, 32, 64));
    rmb = fmaxf(rmb, __shfl_xor(rmb, 32, 64));
    if (lane < 32) {
        red[wave][lane]      = rma;
        red[wave][32 + lane] = rmb;
    }
    __syncthreads();

    if (tid < 64) {                      // wave 0 finalizes 64 queries
        float smax = red[0][tid];
#pragma unroll
        for (int w = 1; w < WPB; ++w) smax = fmaxf(smax, red[w][tid]);
        const int n = qc0 * 32 + tid;
        float qx = qb[n], qy = qb[NPTS + n], qz = qb[2 * NPTS + n];
        float d = fmaxf(qx * qx + qy * qy + qz * qz - 2.0f * smax, 0.0f);
#pragma unroll
        for (int off = 32; off > 0; off >>= 1)
            d += __shfl_down(d, off, 64);
        if (tid == 0)
            atomicAdd(out, d * (2.0f / NB));     // 2 * mean over batches
    }
}

extern "C" void kernel_launch(void* const* d_in, const int* in_sizes, int n_in,
                              void* d_out, int out_size, void* d_ws, size_t ws_size,
                              hipStream_t stream) {
    const float* pc2  = (const float*)d_in[0];
    const float* pc1w = (const float*)d_in[1];
    float* out = (float*)d_out;
    uint4* wsA = (uint4*)d_ws;           // B*256*64*16 B = 1 MiB

    chamfer_prep<<<NB * NPTS / 512, 512, 0, stream>>>(pc1w, wsA, out);
    dim3 g(128, NB);                     // 512 blocks = 2/CU, one round
    chamfer_main<<<g, BT, 0, stream>>>(pc2, wsA, out);
}

// Round 3
// 75.305 us; speedup vs baseline: 1.0596x; 1.0100x over previous
//
#include <hip/hip_runtime.h>

// ChamferLoss: B=4, C=3, N=M=8192 fp32.
// loss = 2 * mean_b( sum_n min_m ||q_n - r_m||^2 ), clamp >= 0.
// s(n,m) = q.r - 0.5*r^2 via v_mfma_f32_32x32x16_bf16, fp32 split as bf16
// hi+lo across K. Fragment math identical to R10-R12 (verified absmax 0.0).
//
// ROUND 13: fix the compute loop's latency/register structure.
// Evidence: removing the whole LDS pipeline (R11->R12) moved total only
// -3.7us => the loop itself is ~6x over its ~2.5us VALU model. Two causes:
//  (1) prefetch depth 1: one 16B L2 load issued per iter, consumed next
//      iter (~60 busy cyc later) vs ~200cyc L2 latency -> ~140cyc stall
//      per iter unless 4 waves/SIMD hide it perfectly.
//  (2) #pragma unroll 4 at __launch_bounds__(512,4) (128-VGPR cap) keeps
//      multiple 32-reg d-tiles live -> spill or occupancy drop.
// Fix: explicit 4-deep named prefetch (p0..p3 / n0..n3, group-of-4 loop,
// loads issued BEFORE the group's 8 MFMAs + 32 max3 => ~240 busy cycles
// in flight >= L2 latency, works even at 2 waves/SIMD), and unroll 1 so
// only one group's state is live (~105 VGPR < 128).

#define NPTS 8192
#define NB   4
#define WPB  8        // waves per block
#define BT   (WPB * 64)
#define CPW  32       // chunks per wave (32 refs each)

typedef float f32x16 __attribute__((ext_vector_type(16)));
typedef short bf16x8 __attribute__((ext_vector_type(8)));

static __device__ __forceinline__ unsigned int f2bf(float f) {
    unsigned int u = __float_as_uint(f);
    u += 0x7FFF + ((u >> 16) & 1);          // RNE
    return u >> 16;
}
static __device__ __forceinline__ float bf2f(unsigned int s) {
    return __uint_as_float(s << 16);
}

// ---- K0: one-time ref -> A-fragment conversion ----
__global__ __launch_bounds__(512) void chamfer_prep(
    const float* __restrict__ pc1w,      // refs [B,3,N]
    uint4* __restrict__ wsA,             // [B][256][64] uint4 = 1 MiB
    float* __restrict__ out)
{
    const int g = blockIdx.x * 512 + threadIdx.x;   // 0..32767, one ref each
    if (g == 0) out[0] = 0.0f;                      // K1 accumulates after
    const int b = g >> 13, i = g & (NPTS - 1);
    const float* refb = pc1w + b * 3 * NPTS;
    float x = refb[i], y = refb[NPTS + i], z = refb[2 * NPTS + i];
    unsigned xh = f2bf(x), yh = f2bf(y), zh = f2bf(z);
    unsigned xl = f2bf(x - bf2f(xh));
    unsigned yl = f2bf(y - bf2f(yh));
    unsigned zl = f2bf(z - bf2f(zh));
    float h = -0.5f * (x * x + y * y + z * z);
    unsigned hh = f2bf(h);
    unsigned hl = f2bf(h - bf2f(hh));
    const int c = i >> 5, l = i & 31;
    // A k0..7 = [xh,xl,xh,yh,yl,yh,zh,zl], k8..15 = [zh,hh,hl,0,...]
    uint4* dst = wsA + (((size_t)b * 256 + c) << 6);
    dst[l]      = make_uint4(xh | (xl << 16), xh | (yh << 16),
                             yl | (yh << 16), zh | (zl << 16));
    dst[32 + l] = make_uint4(zh | (hh << 16), hl, 0u, 0u);
}

static __device__ __forceinline__ bf16x8 make_bfrag(float x, float y, float z,
                                                    int lane)
{
    unsigned xh = f2bf(x), yh = f2bf(y), zh = f2bf(z);
    unsigned xl = f2bf(x - bf2f(xh));
    unsigned yl = f2bf(y - bf2f(yh));
    unsigned zl = f2bf(z - bf2f(zh));
    // B k0..7 = [xh,xh,xl,yh,yh,yl,zh,zh], k8..15 = [zl,1,1,0,...]
    uint4 bu = (lane < 32)
        ? make_uint4(xh | (xh << 16), xl | (yh << 16),
                     yh | (yl << 16), zh | (zh << 16))
        : make_uint4(zl | (0x3F80u << 16), 0x3F80u, 0u, 0u);
    return __builtin_bit_cast(bf16x8, bu);
}

static __device__ __forceinline__ void proc_chunk(
    uint4 av, bf16x8 bq0, bf16x8 bq1, const f32x16& zero,
    float& rma0, float& rma1, float& rma2, float& rma3,
    float& rmb0, float& rmb1, float& rmb2, float& rmb3)
{
    bf16x8 aa = __builtin_bit_cast(bf16x8, av);
    f32x16 d0 = __builtin_amdgcn_mfma_f32_32x32x16_bf16(aa, bq0, zero, 0, 0, 0);
    f32x16 d1 = __builtin_amdgcn_mfma_f32_32x32x16_bf16(aa, bq1, zero, 0, 0, 0);
    // each line is a 3-input max -> v_max3_f32
    rma0 = fmaxf(rma0, fmaxf(d0[0],  d0[1]));   // rows = refs
    rma0 = fmaxf(rma0, fmaxf(d0[2],  d0[3]));
    rma1 = fmaxf(rma1, fmaxf(d0[4],  d0[5]));
    rma1 = fmaxf(rma1, fmaxf(d0[6],  d0[7]));
    rma2 = fmaxf(rma2, fmaxf(d0[8],  d0[9]));
    rma2 = fmaxf(rma2, fmaxf(d0[10], d0[11]));
    rma3 = fmaxf(rma3, fmaxf(d0[12], d0[13]));
    rma3 = fmaxf(rma3, fmaxf(d0[14], d0[15]));
    rmb0 = fmaxf(rmb0, fmaxf(d1[0],  d1[1]));
    rmb0 = fmaxf(rmb0, fmaxf(d1[2],  d1[3]));
    rmb1 = fmaxf(rmb1, fmaxf(d1[4],  d1[5]));
    rmb1 = fmaxf(rmb1, fmaxf(d1[6],  d1[7]));
    rmb2 = fmaxf(rmb2, fmaxf(d1[8],  d1[9]));
    rmb2 = fmaxf(rmb2, fmaxf(d1[10], d1[11]));
    rmb3 = fmaxf(rmb3, fmaxf(d1[12], d1[13]));
    rmb3 = fmaxf(rmb3, fmaxf(d1[14], d1[15]));
}

// ---- K1: fused main kernel, 4-deep register prefetch, no LDS staging ----
__global__ __launch_bounds__(BT, 4) void chamfer_main(
    const float* __restrict__ pc2,       // queries [B,3,N]
    const uint4* __restrict__ wsA,       // precomputed A-fragments
    float* __restrict__ out)
{
    __shared__ float red[WPB][64];       // cross-wave max partials (2 KB)
    const int tid  = threadIdx.x;
    const int wave = tid >> 6;
    const int lane = tid & 63;
    const int b    = blockIdx.y;
    const int qc0  = blockIdx.x * 2;     // 2 query chunks = 64 queries / block

    // per-lane query B-fragments (columns = lane&31 of q-chunks qc0, qc0+1)
    const float* qb = pc2 + b * 3 * NPTS;
    const int qn0 = qc0 * 32 + (lane & 31);
    const int qn1 = qn0 + 32;
    float x0 = qb[qn0], y0 = qb[NPTS + qn0], z0 = qb[2 * NPTS + qn0];
    float x1 = qb[qn1], y1 = qb[NPTS + qn1], z1 = qb[2 * NPTS + qn1];
    bf16x8 bq0 = make_bfrag(x0, y0, z0, lane);
    bf16x8 bq1 = make_bfrag(x1, y1, z1, lane);

    f32x16 zero;
#pragma unroll
    for (int i = 0; i < 16; ++i) zero[i] = 0.0f;

    float rma0 = -3e38f, rma1 = -3e38f, rma2 = -3e38f, rma3 = -3e38f;
    float rmb0 = -3e38f, rmb1 = -3e38f, rmb2 = -3e38f, rmb3 = -3e38f;

    // wave w owns 32 contiguous chunks (1024 refs); chunk c at s[c*64]
    const uint4* s = wsA + (((size_t)b * 256 + wave * CPW) << 6) + lane;

    // 4-deep prefetch: p0..p3 = chunks of the current group of 4
    uint4 p0 = s[0], p1 = s[64], p2 = s[128], p3 = s[192];
#pragma unroll 1
    for (int g = 0; g < (CPW / 4) - 1; ++g) {
        // issue next group's 4 loads FIRST (~240 busy cycles in flight)
        const uint4* nx = s + (g + 1) * 256;
        uint4 n0 = nx[0], n1 = nx[64], n2 = nx[128], n3 = nx[192];
        proc_chunk(p0, bq0, bq1, zero, rma0, rma1, rma2, rma3,
                   rmb0, rmb1, rmb2, rmb3);
        proc_chunk(p1, bq0, bq1, zero, rma0, rma1, rma2, rma3,
                   rmb0, rmb1, rmb2, rmb3);
        proc_chunk(p2, bq0, bq1, zero, rma0, rma1, rma2, rma3,
                   rmb0, rmb1, rmb2, rmb3);
        proc_chunk(p3, bq0, bq1, zero, rma0, rma1, rma2, rma3,
                   rmb0, rmb1, rmb2, rmb3);
        p0 = n0; p1 = n1; p2 = n2; p3 = n3;
    }
    proc_chunk(p0, bq0, bq1, zero, rma0, rma1, rma2, rma3,
               rmb0, rmb1, rmb2, rmb3);
    proc_chunk(p1, bq0, bq1, zero, rma0, rma1, rma2, rma3,
               rmb0, rmb1, rmb2, rmb3);
    proc_chunk(p2, bq0, bq1, zero, rma0, rma1, rma2, rma3,
               rmb0, rmb1, rmb2, rmb3);
    proc_chunk(p3, bq0, bq1, zero, rma0, rma1, rma2, rma3,
               rmb0, rmb1, rmb2, rmb3);

    float rma = fmaxf(fmaxf(rma0, rma1), fmaxf(rma2, rma3));
    float rmb = fmaxf(fmaxf(rmb0, rmb1), fmaxf(rmb2, rmb3));
    // lanes l and l^32 hold the two row-halves of the same query column
    rma = fmaxf(rma, __shfl_xor(rma, 32, 64));
    rmb = fmaxf(rmb, __shfl_xor(rmb, 32, 64));
    if (lane < 32) {
        red[wave][lane]      = rma;
        red[wave][32 + lane] = rmb;
    }
    __syncthreads();

    if (tid < 64) {                      // wave 0 finalizes 64 queries
        float smax = red[0][tid];
#pragma unroll
        for (int w = 1; w < WPB; ++w) smax = fmaxf(smax, red[w][tid]);
        const int n = qc0 * 32 + tid;
        float qx = qb[n], qy = qb[NPTS + n], qz = qb[2 * NPTS + n];
        float d = fmaxf(qx * qx + qy * qy + qz * qz - 2.0f * smax, 0.0f);
#pragma unroll
        for (int off = 32; off > 0; off >>= 1)
            d += __shfl_down(d, off, 64);
        if (tid == 0)
            atomicAdd(out, d * (2.0f / NB));     // 2 * mean over batches
    }
}

extern "C" void kernel_launch(void* const* d_in, const int* in_sizes, int n_in,
                              void* d_out, int out_size, void* d_ws, size_t ws_size,
                              hipStream_t stream) {
    const float* pc2  = (const float*)d_in[0];
    const float* pc1w = (const float*)d_in[1];
    float* out = (float*)d_out;
    uint4* wsA = (uint4*)d_ws;           // B*256*64*16 B = 1 MiB

    chamfer_prep<<<NB * NPTS / 512, 512, 0, stream>>>(pc1w, wsA, out);
    dim3 g(128, NB);                     // 512 blocks = 2/CU, one round
    chamfer_main<<<g, BT, 0, stream>>>(pc2, wsA, out);
}